// Round 3
// baseline (79.870 us; speedup 1.0000x reference)
//
#include <hip/hip_runtime.h>

typedef __attribute__((ext_vector_type(8))) short short8;
typedef __attribute__((ext_vector_type(4))) float f32x4;

#define B_TOTAL 20000
#define NF      256
#define K2      512
#define NS      10

__device__ __forceinline__ unsigned short f2bf(float x) {
    unsigned u = __builtin_bit_cast(unsigned, x);
    u += 0x7FFFu + ((u >> 16) & 1u);   // round-to-nearest-even
    return (unsigned short)(u >> 16);
}

__device__ __forceinline__ float4 add4(float4 a, float4 b) {
    return make_float4(a.x + b.x, a.y + b.y, a.z + b.z, a.w + b.w);
}

// K1: one wave per b-row. Scalar (s_load) indices, 11 independent float4 row
// loads, tree sum, coalesced bf16 write. Blocks 0..127 also convert W->bf16.
__global__ __launch_bounds__(256) void gather(
    const float* __restrict__ ue, const int* __restrict__ nidx,
    const int* __restrict__ nodes, const float* __restrict__ w,
    unsigned short* __restrict__ comb, unsigned short* __restrict__ wbf)
{
    const int t = threadIdx.x, blk = blockIdx.x;
    if (blk < 128) {                     // 128 * 256 * 4 = 131072 = 256*512 W elems
        const int base = blk * 1024 + t * 4;
        const float4 v = *(const float4*)(w + base);
        ushort4 o;
        o.x = f2bf(v.x); o.y = f2bf(v.y); o.z = f2bf(v.z); o.w = f2bf(v.w);
        *(ushort4*)(wbf + base) = o;
    }
    const int lane = t & 63;
    const int wv = __builtin_amdgcn_readfirstlane(t >> 6);   // force wave-uniform
    const int b = blk * 4 + wv;
    if (b >= B_TOTAL) return;

    const int* ip = nidx + (size_t)b * NS;   // uniform -> scalar loads
    const int node = nodes[b];               // uniform -> scalar load

    const float4 sf = ((const float4*)(ue + (size_t)node * NF))[lane];
    float4 a[NS];
    #pragma unroll
    for (int s = 0; s < NS; ++s)
        a[s] = ((const float4*)(ue + (size_t)ip[s] * NF))[lane];

    // pairwise tree sum (depth 4)
    float4 s01 = add4(a[0], a[1]), s23 = add4(a[2], a[3]);
    float4 s45 = add4(a[4], a[5]), s67 = add4(a[6], a[7]);
    float4 s89 = add4(a[8], a[9]);
    float4 t0 = add4(s01, s23), t1 = add4(s45, s67);
    float4 sum = add4(add4(t0, t1), s89);

    const float inv = 1.0f / 11.0f;          // reference divides by S+1
    ushort4 s4, n4;
    s4.x = f2bf(sf.x); s4.y = f2bf(sf.y); s4.z = f2bf(sf.z); s4.w = f2bf(sf.w);
    n4.x = f2bf(sum.x * inv); n4.y = f2bf(sum.y * inv);
    n4.z = f2bf(sum.z * inv); n4.w = f2bf(sum.w * inv);

    unsigned short* crow = comb + (size_t)b * K2;
    *(ushort4*)(crow + lane * 4) = s4;           // self: 512 B contiguous per wave
    *(ushort4*)(crow + NF + lane * 4) = n4;      // neigh-mean: 512 B contiguous
}

// K2: out[e][b] = relu(sum_k W[e][k]*comb[b][k]). No LDS, no barriers.
// Grid (625, 2), block 256. Wave tile 32e x 32b, fragments read direct from
// global (W L2-hot, comb tile L1-hot after first touch).
__global__ __launch_bounds__(256) void gemm_relu(
    const unsigned short* __restrict__ wbf,   // [256][512] bf16
    const unsigned short* __restrict__ comb,  // [20000][512] bf16
    float* __restrict__ out)                  // [256][20000] f32
{
    const int t = threadIdx.x;
    const int lane = t & 63;
    const int wv = t >> 6;
    const int n0 = blockIdx.x * 32;
    const int e0 = blockIdx.y * 128 + wv * 32;
    const int fr = lane & 15;
    const int kq = lane >> 4;

    const unsigned short* wp = wbf  + (size_t)(e0 + fr) * K2 + kq * 8;
    const unsigned short* cp = comb + (size_t)(n0 + fr) * K2 + kq * 8;

    f32x4 acc[2][2] = {};
    #pragma unroll 4
    for (int ks = 0; ks < 16; ++ks) {
        short8 af[2], bg[2];
        af[0] = *(const short8*)(wp + ks * 32);
        af[1] = *(const short8*)(wp + (size_t)16 * K2 + ks * 32);
        bg[0] = *(const short8*)(cp + ks * 32);
        bg[1] = *(const short8*)(cp + (size_t)16 * K2 + ks * 32);
        #pragma unroll
        for (int i = 0; i < 2; ++i)
            #pragma unroll
            for (int j = 0; j < 2; ++j)
                acc[i][j] = __builtin_amdgcn_mfma_f32_16x16x32_bf16(af[i], bg[j], acc[i][j], 0, 0, 0);
    }

    #pragma unroll
    for (int i = 0; i < 2; ++i) {
        const int e = e0 + i * 16 + kq * 4;
        #pragma unroll
        for (int j = 0; j < 2; ++j) {
            const int b = n0 + j * 16 + fr;
            #pragma unroll
            for (int r = 0; r < 4; ++r)
                out[(size_t)(e + r) * B_TOTAL + b] = fmaxf(acc[i][j][r], 0.0f);
        }
    }
}

extern "C" void kernel_launch(void* const* d_in, const int* in_sizes, int n_in,
                              void* d_out, int out_size, void* d_ws, size_t ws_size,
                              hipStream_t stream) {
    const float* ue    = (const float*)d_in[0];
    // d_in[1] = features_ap: unused (ue2ue mode)
    const int*   nidx  = (const int*)d_in[2];
    const int*   nodes = (const int*)d_in[3];
    const float* w     = (const float*)d_in[4];
    float*       out   = (float*)d_out;

    unsigned short* comb = (unsigned short*)d_ws;              // [20000][512] bf16 = 20.48 MB
    unsigned short* wbf  = comb + (size_t)B_TOTAL * K2;        // [256][512] bf16 = 0.26 MB

    hipLaunchKernelGGL(gather, dim3(5000), dim3(256), 0, stream,
                       ue, nidx, nodes, w, comb, wbf);
    hipLaunchKernelGGL(gemm_relu, dim3(625, 2), dim3(256), 0, stream,
                       wbf, comb, out);
}

// Round 4
// 68.156 us; speedup vs baseline: 1.1719x; 1.1719x over previous
//
#include <hip/hip_runtime.h>

typedef __attribute__((ext_vector_type(8))) short short8;
typedef __attribute__((ext_vector_type(4))) float f32x4;

#define B_TOTAL 20000
#define B_PAD   20096   // 628 * 32 = 5024 * 4
#define NF      256
#define K2      512
#define NS      10

__device__ __forceinline__ unsigned short f2bf(float x) {
    unsigned u = __builtin_bit_cast(unsigned, x);
    u += 0x7FFFu + ((u >> 16) & 1u);   // round-to-nearest-even
    return (unsigned short)(u >> 16);
}

// K1 (round-1 proven form): one wave per b-row; per-lane idx loads + shfl;
// 11 independent 1KB row loads in flight; coalesced bf16 row write.
// Blocks 0..127 also convert W f32->bf16.
__global__ __launch_bounds__(256) void gather_combine(
    const float* __restrict__ ue, const int* __restrict__ nidx,
    const int* __restrict__ nodes, const float* __restrict__ w,
    unsigned short* __restrict__ comb, unsigned short* __restrict__ wbf)
{
    const int t = threadIdx.x, blk = blockIdx.x;
    if (blk < 128) {                       // 128 * 256 * 4 = 256*512 W elems
        const int base = blk * 1024 + t * 4;
        const float4 v = *(const float4*)(w + base);
        ushort4 o;
        o.x = f2bf(v.x); o.y = f2bf(v.y); o.z = f2bf(v.z); o.w = f2bf(v.w);
        *(ushort4*)(wbf + base) = o;
    }
    const int lane = t & 63;
    const int b = blk * 4 + (t >> 6);      // one wave per b-row
    if (b >= B_PAD) return;
    unsigned short* crow = comb + (size_t)b * K2;
    if (b < B_TOTAL) {
        const int node = nodes[b];
        const float4 sf = ((const float4*)(ue + (size_t)node * NF))[lane];
        int myidx = 0;
        if (lane < NS) myidx = nidx[b * NS + lane];
        float ax = 0.f, ay = 0.f, az = 0.f, aw = 0.f;
        #pragma unroll
        for (int s = 0; s < NS; ++s) {
            const int is = __shfl(myidx, s);
            const float4 v = ((const float4*)(ue + (size_t)is * NF))[lane];
            ax += v.x; ay += v.y; az += v.z; aw += v.w;
        }
        const float inv = 1.0f / 11.0f;    // reference divides by S+1
        ushort4 s4, n4;
        s4.x = f2bf(sf.x); s4.y = f2bf(sf.y); s4.z = f2bf(sf.z); s4.w = f2bf(sf.w);
        n4.x = f2bf(ax * inv); n4.y = f2bf(ay * inv);
        n4.z = f2bf(az * inv); n4.w = f2bf(aw * inv);
        *(ushort4*)(crow + lane * 4) = s4;
        *(ushort4*)(crow + NF + lane * 4) = n4;
    } else {                               // zero pad rows (ws is poisoned)
        ushort4 z; z.x = z.y = z.z = z.w = 0;
        *(ushort4*)(crow + lane * 4) = z;
        *(ushort4*)(crow + NF + lane * 4) = z;
    }
}

// K2: out[e][b] = relu(sum_k W[e][k]*comb[b][k]).
// Tile 32(b) x 128(e), BK=64, grid (628,2) = 1256 blocks (~4.9/CU, all resident).
// LDS: A [g8][row128][8] = 16KB, B [g8][row32][8] = 4KB; conflict-free b128 reads.
__global__ __launch_bounds__(256) void gemm_relu(
    const unsigned short* __restrict__ wbf,   // [256][512] bf16
    const unsigned short* __restrict__ comb,  // [B_PAD][512] bf16
    float* __restrict__ out)                  // [256][20000] f32
{
    __shared__ unsigned short Alds[8192];  // 16 KB
    __shared__ unsigned short Blds[2048];  //  4 KB
    const int t    = threadIdx.x;
    const int lane = t & 63;
    const int wv   = t >> 6;               // wave owns e-rows [wv*32, wv*32+32)
    const int n0   = blockIdx.x * 32;      // b-tile
    const int m0   = blockIdx.y * 128;     // e-tile
    const int fr   = lane & 15;
    const int kq   = lane >> 4;

    f32x4 acc[2][2] = {};
    const short8* A8 = (const short8*)Alds;
    const short8* B8 = (const short8*)Blds;

    for (int ks = 0; ks < 8; ++ks) {
        // stage A: 4 x 16B per thread; dest linear in (L*256+t) -> wave-uniform base + lane*16
        #pragma unroll
        for (int L = 0; L < 4; ++L) {
            const int d16 = L * 256 + t;
            const int g = d16 >> 7, row = d16 & 127;
            const unsigned short* src = wbf + (size_t)(m0 + row) * K2 + ks * 64 + g * 8;
            __builtin_amdgcn_global_load_lds(
                (const __attribute__((address_space(1))) void*)src,
                (__attribute__((address_space(3))) void*)(Alds + (size_t)d16 * 8), 16, 0, 0);
        }
        // stage B: 1 x 16B per thread
        {
            const int g = t >> 5, row = t & 31;
            const unsigned short* src = comb + (size_t)(n0 + row) * K2 + ks * 64 + g * 8;
            __builtin_amdgcn_global_load_lds(
                (const __attribute__((address_space(1))) void*)src,
                (__attribute__((address_space(3))) void*)(Blds + (size_t)t * 8), 16, 0, 0);
        }
        asm volatile("s_waitcnt vmcnt(0)" ::: "memory");
        __syncthreads();

        #pragma unroll
        for (int h = 0; h < 2; ++h) {      // two 32-wide k-halves of BK=64
            short8 af[2], bg[2];
            #pragma unroll
            for (int i = 0; i < 2; ++i)
                af[i] = A8[(h * 4 + kq) * 128 + wv * 32 + i * 16 + fr];
            #pragma unroll
            for (int j = 0; j < 2; ++j)
                bg[j] = B8[(h * 4 + kq) * 32 + j * 16 + fr];
            #pragma unroll
            for (int i = 0; i < 2; ++i)
                #pragma unroll
                for (int j = 0; j < 2; ++j)
                    acc[i][j] = __builtin_amdgcn_mfma_f32_16x16x32_bf16(af[i], bg[j], acc[i][j], 0, 0, 0);
        }
        __syncthreads();
    }

    #pragma unroll
    for (int i = 0; i < 2; ++i) {
        const int e = m0 + wv * 32 + i * 16 + kq * 4;
        #pragma unroll
        for (int j = 0; j < 2; ++j) {
            const int b = n0 + j * 16 + fr;
            if (b < B_TOTAL) {
                #pragma unroll
                for (int r = 0; r < 4; ++r)
                    out[(size_t)(e + r) * B_TOTAL + b] = fmaxf(acc[i][j][r], 0.0f);
            }
        }
    }
}

extern "C" void kernel_launch(void* const* d_in, const int* in_sizes, int n_in,
                              void* d_out, int out_size, void* d_ws, size_t ws_size,
                              hipStream_t stream) {
    const float* ue    = (const float*)d_in[0];
    // d_in[1] = features_ap: unused (ue2ue mode)
    const int*   nidx  = (const int*)d_in[2];
    const int*   nodes = (const int*)d_in[3];
    const float* w     = (const float*)d_in[4];
    float*       out   = (float*)d_out;

    unsigned short* comb = (unsigned short*)d_ws;              // [B_PAD][512] bf16 = 20.58 MB
    unsigned short* wbf  = comb + (size_t)B_PAD * K2;          // [256][512] bf16  = 0.26 MB

    hipLaunchKernelGGL(gather_combine, dim3(B_PAD / 4), dim3(256), 0, stream,
                       ue, nidx, nodes, w, comb, wbf);
    hipLaunchKernelGGL(gemm_relu, dim3(B_PAD / 32, 2), dim3(256), 0, stream,
                       wbf, comb, out);
}

// Round 5
// 67.602 us; speedup vs baseline: 1.1815x; 1.0082x over previous
//
#include <hip/hip_runtime.h>

typedef __attribute__((ext_vector_type(8))) short short8;
typedef __attribute__((ext_vector_type(4))) float f32x4;

#define B_TOTAL 20000
#define BT      16          // b-rows per block; 20000 = 1250*16 exactly
#define NBLK    1250
#define NF      256
#define K2      512
#define NS      10

__device__ __forceinline__ unsigned short f2bf(float x) {
    unsigned u = __builtin_bit_cast(unsigned, x);
    u += 0x7FFFu + ((u >> 16) & 1u);   // round-to-nearest-even
    return (unsigned short)(u >> 16);
}

// K0: W [256][512] f32 -> bf16 (tiny, ~1 us)
__global__ __launch_bounds__(256) void wconvert(const float* __restrict__ w,
                                                unsigned short* __restrict__ wbf) {
    const int i = (blockIdx.x * 256 + threadIdx.x) * 4;
    const float4 v = *(const float4*)(w + i);
    ushort4 o;
    o.x = f2bf(v.x); o.y = f2bf(v.y); o.z = f2bf(v.z); o.w = f2bf(v.w);
    *(ushort4*)(wbf + i) = o;
}

// Fused: gather 16 b-rows into swizzled LDS, one barrier, then 256e x 16b GEMM.
// LDS comb: [row 16][1024 B], logical byte ^ ((row&7)<<4)  (T2 XOR swizzle).
// grid 1250 (4.9 blocks/CU co-resident), block 256 (4 waves).
__global__ __launch_bounds__(256, 4) void fused(
    const float* __restrict__ ue, const int* __restrict__ nidx,
    const int* __restrict__ nodes, const unsigned short* __restrict__ wbf,
    float* __restrict__ out)
{
    __shared__ unsigned short comb[BT * K2];   // 16 KB
    const int t    = threadIdx.x;
    const int lane = t & 63;
    const int wv   = t >> 6;
    const int bbase = blockIdx.x * BT;

    // ---- Phase 1: each wave gathers 4 rows ----
    {
        const int r0 = wv * 4;
        const int b0 = bbase + r0;
        // bulk index prefetch: 40 contiguous nidx + 4 nodes per wave
        int nv = 0;
        if (lane < 40)      nv = nidx[b0 * NS + lane];
        else if (lane < 44) nv = nodes[b0 + (lane - 40)];

        for (int r = 0; r < 4; ++r) {          // rolled: ~11 loads in flight/wave
            const int row = r0 + r;
            const int nd  = __shfl(nv, 40 + r);
            const float4 sf = ((const float4*)(ue + (size_t)nd * NF))[lane];
            float ax = 0.f, ay = 0.f, az = 0.f, aw = 0.f;
            #pragma unroll
            for (int s = 0; s < NS; ++s) {
                const int is = __shfl(nv, r * NS + s);
                const float4 v = ((const float4*)(ue + (size_t)is * NF))[lane];
                ax += v.x; ay += v.y; az += v.z; aw += v.w;
            }
            const float inv = 1.0f / 11.0f;    // reference divides by S+1
            ushort4 s4, n4;
            s4.x = f2bf(sf.x); s4.y = f2bf(sf.y); s4.z = f2bf(sf.z); s4.w = f2bf(sf.w);
            n4.x = f2bf(ax * inv); n4.y = f2bf(ay * inv);
            n4.z = f2bf(az * inv); n4.w = f2bf(aw * inv);
            const int swz = (row & 7) << 4;
            char* base = (char*)comb + row * 1024;
            *(ushort4*)(base + ((lane * 8)       ^ swz)) = s4;   // self half  (k<256)
            *(ushort4*)(base + ((512 + lane * 8) ^ swz)) = n4;   // neigh half (k>=256)
        }
    }
    __syncthreads();

    // ---- Phase 2: GEMM, no barriers. Wave wv owns e-rows [wv*64, wv*64+64). ----
    const int fr = lane & 15;
    const int kq = lane >> 4;
    const unsigned short* wp = wbf + (size_t)(wv * 64 + fr) * K2 + kq * 8;
    const char* cbase = (const char*)comb + fr * 1024;
    const int swzR = (fr & 7) << 4;

    f32x4 acc[4] = {};
    #pragma unroll 4
    for (int ks = 0; ks < 16; ++ks) {
        const short8 bg = *(const short8*)(cbase + ((ks * 64 + kq * 16) ^ swzR));
        short8 af[4];
        #pragma unroll
        for (int i = 0; i < 4; ++i)
            af[i] = *(const short8*)(wp + (size_t)i * 16 * K2 + ks * 32);
        #pragma unroll
        for (int i = 0; i < 4; ++i)
            acc[i] = __builtin_amdgcn_mfma_f32_16x16x32_bf16(af[i], bg, acc[i], 0, 0, 0);
    }

    // ---- Epilogue: relu + store (16 lanes x 4B = one 64B line per store) ----
    const int col = bbase + fr;
    #pragma unroll
    for (int i = 0; i < 4; ++i) {
        const int e = wv * 64 + i * 16 + kq * 4;
        #pragma unroll
        for (int r = 0; r < 4; ++r)
            out[(size_t)(e + r) * B_TOTAL + col] = fmaxf(acc[i][r], 0.0f);
    }
}

extern "C" void kernel_launch(void* const* d_in, const int* in_sizes, int n_in,
                              void* d_out, int out_size, void* d_ws, size_t ws_size,
                              hipStream_t stream) {
    const float* ue    = (const float*)d_in[0];
    // d_in[1] = features_ap: unused (ue2ue mode)
    const int*   nidx  = (const int*)d_in[2];
    const int*   nodes = (const int*)d_in[3];
    const float* w     = (const float*)d_in[4];
    float*       out   = (float*)d_out;

    unsigned short* wbf = (unsigned short*)d_ws;   // [256][512] bf16 = 256 KB

    hipLaunchKernelGGL(wconvert, dim3(128), dim3(256), 0, stream, w, wbf);
    hipLaunchKernelGGL(fused, dim3(NBLK), dim3(256), 0, stream,
                       ue, nidx, nodes, wbf, out);
}